// Round 12
// baseline (68.065 us; speedup 1.0000x reference)
//
#include <hip/hip_runtime.h>
#include <stdint.h>

// Problem constants (LSHSoftmax): B=1024, D=512, N=500000, S=32768
#define B_DIM 1024
#define D_DIM 512
#define S_DIM 32768

typedef __attribute__((ext_vector_type(8))) short bf16x8;   // 8 bf16 = 4 VGPRs
typedef __attribute__((ext_vector_type(4))) float f32x4;
typedef __attribute__((ext_vector_type(8))) unsigned short u16x8;

#define AS1 __attribute__((address_space(1)))
#define AS3 __attribute__((address_space(3)))

__device__ __forceinline__ unsigned short f2bf(float f) {
  union { float f; uint32_t u; } x; x.f = f;
  uint32_t r = x.u + 0x7fffu + ((x.u >> 16) & 1u);   // RNE
  return (unsigned short)(r >> 16);
}
__device__ __forceinline__ uint32_t cvtpk(float a, float b) {
  uint32_t r;
  asm("v_cvt_pk_bf16_f32 %0, %1, %2" : "=v"(r) : "v"(a), "v"(b));
  return r;
}

// Convert inputs A f32 -> bf16 once (1 MiB; L2-resident for all GEMM blocks).
__global__ __launch_bounds__(256) void conv_a(const float* __restrict__ A,
                                              unsigned short* __restrict__ Ab) {
  int gid = blockIdx.x * 256 + threadIdx.x;
  const float* src = A + (size_t)gid * 8;
  float4 v0 = *(const float4*)src;
  float4 v1 = *(const float4*)(src + 4);
  u16x8 o;
  o[0] = f2bf(v0.x); o[1] = f2bf(v0.y); o[2] = f2bf(v0.z); o[3] = f2bf(v0.w);
  o[4] = f2bf(v1.x); o[5] = f2bf(v1.y); o[6] = f2bf(v1.z); o[7] = f2bf(v1.w);
  *(u16x8*)(Ab + (size_t)gid * 8) = o;
}

// ---------------------------------------------------------------------------
// Persistent-panel fused gather+GEMM, 64x64 wave tiles (LDS-read balanced).
// 256 blocks (1/CU), block b owns cols n0=b*128, ALL 1024 rows as 4 M-chunks
// of 256:
//  Phase 1 (once): gather W[ids[n0..+127]][:] f32 (read ONCE from HBM) ->
//    cvt_pk bf16 -> swizzled persistent 128 KB LDS panel. stage(0) prefetch
//    issued first so tile 0 loads under the gather. One __syncthreads().
//  Phase 2: 64 iters (g = mc*16 + kt): stage 256x32 A-chunk (16 KB, 2 gload
//    /wave, double-buffered), vmcnt(2), raw barriers, 8 waves as 4M x 2N
//    (wave tile 64x64): 8 ds_read_b128 + 16 MFMA per wave per iter
//    -> LDS pipe ~640 cyc == MFMA pipe ~620 cyc (r11 was 12 reads, LDS-bound).
//    Epilogue per M-chunk (fire-and-forget stores, retire via L2).
// LDS: A 2x16 KB @0 + B 128 KB @32768 = 160 KB exactly.
// B swizzle: [col][64 slots], slot = kslot ^ (col&7) -> frag reads 2-way.
// A swizzle: row pairs in 128B lines, slot = (((row&1)<<2)|lq) ^ ((row>>1)&7)
//   -> frag reads 2-way (free); gload dest linear, source inverse-permuted.
// ---------------------------------------------------------------------------
#define BN 128
#define NG 64                        // 4 mc x 16 kt
#define B_OFF 32768

__global__ __launch_bounds__(512, 2) void gemm_fused(const unsigned short* __restrict__ Ab,
                                                     const float* __restrict__ W,
                                                     const float* __restrict__ bias,
                                                     const int* __restrict__ ids,
                                                     float* __restrict__ out) {
  __shared__ __attribute__((aligned(16))) char lds[163840];   // 160 KiB

  const int tid = threadIdx.x;
  const int lane = tid & 63;
  const int w = tid >> 6;            // wave 0..7
  const int wm = w >> 1;             // M-group 0..3 (64 rows of the 256-chunk)
  const int wn = w & 1;              // N-group 0..1 (64 cols)
  const int lq = lane >> 4;          // 0..3
  const int l16 = lane & 15;
  const int n0 = blockIdx.x * BN;

  // A stage source (swizzle-inverse of the read layout). Physical 16B slot
  // p = j*512+tid of a 16 KB tile: line=p>>3, sl=(p&7)^(line&7),
  // row=2*line+(sl>>2), k-quarter=sl&3.
  const char* srcA[2];
#pragma unroll
  for (int j = 0; j < 2; ++j) {
    const int p = j * 512 + tid;
    const int line = p >> 3;
    const int sl = (p & 7) ^ (line & 7);
    const int row = line * 2 + (sl >> 2);
    srcA[j] = (const char*)Ab + row * 1024 + (sl & 3) * 16;
  }
  auto stage = [&](int g) {          // tile g: mc=g>>4 (256 rows), kt=g&15 (K32)
    const int off = (g >> 4) * 262144 + (g & 15) * 64;
    char* dst = lds + (g & 1) * 16384 + w * 1024;
#pragma unroll
    for (int j = 0; j < 2; ++j)
      __builtin_amdgcn_global_load_lds((const AS1 void*)(srcA[j] + off),
                                       (AS3 void*)(dst + j * 8192), 16, 0, 0);
  };

  stage(0);                          // prefetch tile 0 under the gather

  // ---- Phase 1: gather + convert the persistent B panel (once) ----
  {
    const int row = tid >> 2;        // 0..127 (block-local col)
    const int c = tid & 3;           // 4 threads per row, 32B f32 each per j
    const int myid = ids[n0 + row];
    const float* srcW = W + (size_t)myid * D_DIM;
    char* drow = lds + B_OFF + row * 1024;
    const int r7 = row & 7;
#pragma unroll
    for (int j = 0; j < 16; ++j) {
      const float* p = srcW + j * 32 + c * 8;
      float4 a = *(const float4*)p;
      float4 b = *(const float4*)(p + 4);
      int4 o;
      o.x = cvtpk(a.x, a.y); o.y = cvtpk(a.z, a.w);
      o.z = cvtpk(b.x, b.y); o.w = cvtpk(b.z, b.w);
      const int slot = (c + j * 4) ^ r7;    // slot sl holds k [sl*8, sl*8+8)
      *(int4*)(drow + slot * 16) = o;
    }
  }
  // bias for the epilogue (4 values/lane), issued before the sync drain.
  float bb[4];
#pragma unroll
  for (int n = 0; n < 4; ++n)
    bb[n] = bias[ids[n0 + wn * 64 + n * 16 + l16]];

  __syncthreads();                   // drains vmcnt+lgkmcnt: panel + tile 0 ready

  // Fragment address pieces.
  int aoff[4];
#pragma unroll
  for (int m = 0; m < 4; ++m) {
    const int row = wm * 64 + m * 16 + l16;
    const int s = (((row & 1) << 2) | lq) ^ ((row >> 1) & 7);
    aoff[m] = (row >> 1) * 128 + s * 16;
  }
  int bbase[4], bx7[4];
#pragma unroll
  for (int n = 0; n < 4; ++n) {
    const int col = wn * 64 + n * 16 + l16;
    bbase[n] = B_OFF + col * 1024;
    bx7[n] = col & 7;
  }

  f32x4 acc[4][4];
#pragma unroll
  for (int m = 0; m < 4; ++m)
#pragma unroll
    for (int n = 0; n < 4; ++n)
      acc[m][n] = (f32x4)0.0f;

  for (int g = 0; g < NG; ++g) {
    __builtin_amdgcn_sched_barrier(0);
    if (g < NG - 1) {
      stage(g + 1);                  // other buffer, released at barrier g-1
      __builtin_amdgcn_sched_barrier(0);
      asm volatile("s_waitcnt vmcnt(2)" ::: "memory");   // tile g landed
    } else {
      asm volatile("s_waitcnt vmcnt(0)" ::: "memory");
    }
    __builtin_amdgcn_s_barrier();    // raw barrier: no full drain
    __builtin_amdgcn_sched_barrier(0);

    const char* bufa = lds + (g & 1) * 16384;
    const int kt4 = (g & 15) << 2;   // kslot base for this K32

    bf16x8 af[4], bv[4];
#pragma unroll
    for (int m = 0; m < 4; ++m)
      af[m] = *(const bf16x8*)(bufa + aoff[m]);
#pragma unroll
    for (int n = 0; n < 4; ++n)
      bv[n] = *(const bf16x8*)(lds + bbase[n] + (((kt4 + lq) ^ bx7[n]) << 4));

    __builtin_amdgcn_s_setprio(1);
#pragma unroll
    for (int m = 0; m < 4; ++m)
#pragma unroll
      for (int n = 0; n < 4; ++n)
        acc[m][n] = __builtin_amdgcn_mfma_f32_16x16x32_bf16(af[m], bv[n],
                                                            acc[m][n], 0, 0, 0);
    __builtin_amdgcn_s_setprio(0);

    __builtin_amdgcn_sched_barrier(0);
    __builtin_amdgcn_s_barrier();    // all waves done with buf g&1

    if ((g & 15) == 15) {
      // ---- Epilogue for mc = g>>4 (col=l16, row=lq*4+r), reset acc ----
      const int rt = (g >> 4) * 256 + wm * 64 + lq * 4;
#pragma unroll
      for (int n = 0; n < 4; ++n) {
        const int col = n0 + wn * 64 + n * 16 + l16;
#pragma unroll
        for (int m = 0; m < 4; ++m) {
          const int rbase = rt + m * 16;
#pragma unroll
          for (int r = 0; r < 4; ++r)
            out[(size_t)(rbase + r) * S_DIM + col] = acc[m][n][r] + bb[n];
          acc[m][n] = (f32x4)0.0f;
        }
      }
    }
  }
}

extern "C" void kernel_launch(void* const* d_in, const int* in_sizes, int n_in,
                              void* d_out, int out_size, void* d_ws, size_t ws_size,
                              hipStream_t stream) {
  const float* inp  = (const float*)d_in[0];   // [B, D] f32
  const float* W    = (const float*)d_in[1];   // [N, D] f32
  const float* bias = (const float*)d_in[2];   // [N] f32
  const int*   ids  = (const int*)d_in[3];     // [S] int32
  float* out = (float*)d_out;                  // [B, S] f32

  unsigned short* Ab = (unsigned short*)d_ws;  // [B, D] bf16 (1 MiB)

  conv_a<<<(B_DIM * D_DIM / 8) / 256, 256, 0, stream>>>(inp, Ab);

  dim3 grid(S_DIM / BN);                       // 256 blocks = 1 per CU
  gemm_fused<<<grid, 512, 0, stream>>>(Ab, W, bias, ids, out);
}